// Round 14
// baseline (342.712 us; speedup 1.0000x reference)
//
#include <hip/hip_runtime.h>
#include <stdint.h>

// Superpoint pooling via 29-bit key bitmap + prefix-popcount ranking.
// key = batch(2b)|qx(9b)|qy(9b)|qz(9b); numeric order == lex order, so exclusive
// prefix popcount over the presence bitmap == jnp.unique sorted rank.
// R14: k5 tile halved (32 ranks/wave, 2x blocks) to cut VGPR 128->~90 and lift
// occupancy — k5 is latency-bound on the random feature gather (403MB moved in
// 157µs = 40% of stream BW), so TLP is the remaining lever. Prefix side
// byte-identical to R13 (measured best).

static constexpr uint32_t NWORDS = 1u << 24;        // 2^29 bits / 32
static constexpr uint32_t NBLK   = NWORDS / 1024;   // 16384 scan blocks
static constexpr uint32_t MCAP   = 65536;           // multi-voxel slot capacity

typedef __attribute__((ext_vector_type(8))) short short8;
typedef __attribute__((ext_vector_type(4))) float f32x4;

__device__ __forceinline__ short f2bf(float x) {
    union { float f; uint32_t u; } v; v.f = x;
    uint32_t u = v.u;
    uint32_t r = (u + 0x7FFFu + ((u >> 16) & 1u)) >> 16;   // RNE
    return (short)r;
}

__device__ __forceinline__ uint32_t point_key(float4 c) {
    uint32_t b  = (uint32_t)(int)c.x;
    uint32_t qx = (uint32_t)(int)floorf(c.y / 0.1f);
    uint32_t qy = (uint32_t)(int)floorf(c.z / 0.1f);
    uint32_t qz = (uint32_t)(int)floorf(c.w / 0.1f);
    return (b << 27) | (qx << 18) | (qy << 9) | qz;
}

__global__ void k1_keys(const float4* __restrict__ coords, uint32_t* __restrict__ bitmap, int N) {
    int i = blockIdx.x * blockDim.x + threadIdx.x;
    if (i >= N) return;
    uint32_t key = point_key(coords[i]);
    atomicOr(&bitmap[key >> 5], 1u << (key & 31u));   // fire-and-forget: no read-back
}

// 1024 words/block, 256 threads, 4 words/thread via uint4, wave-shuffle scan.
// scan4[w>>2]: exclusive popcount prefix within block at 4-word granularity
// (max 255*128 = 32640, fits u16).
__global__ __launch_bounds__(256) void k2a_blockscan(
        const uint4* __restrict__ bm4, uint16_t* __restrict__ scan4,
        uint32_t* __restrict__ bsum) {
    int t = threadIdx.x;
    int lane = t & 63, wid = t >> 6;
    uint4 v = bm4[(size_t)blockIdx.x * 256 + t];
    uint32_t pc = __popc(v.x) + __popc(v.y) + __popc(v.z) + __popc(v.w);
    uint32_t sc = pc;
    #pragma unroll
    for (int off = 1; off < 64; off <<= 1) {
        uint32_t n = __shfl_up(sc, off);
        if (lane >= off) sc += n;
    }
    __shared__ uint32_t wt[4];
    if (lane == 63) wt[wid] = sc;
    __syncthreads();
    uint32_t wbase = 0;
    #pragma unroll
    for (int w = 0; w < 4; ++w) wbase += (w < wid) ? wt[w] : 0u;
    scan4[(size_t)blockIdx.x * 256 + t] = (uint16_t)(wbase + sc - pc);
    if (t == 255) bsum[blockIdx.x] = wbase + sc;
}

// Exclusive scan of 16384 block sums; bscan[16384] = total unique count U.
// Fused: W2 -> bf16 transposed (W2T[col*64+k] = bf16(W2[k*64+col])).
__global__ void k2b_topscan(const uint32_t* __restrict__ bsum, uint32_t* __restrict__ bscan,
                            const float* __restrict__ W2, short* __restrict__ W2T) {
    __shared__ uint32_t s[1024];
    int t = threadIdx.x;
    // folded k0: 4096 elements over 1024 threads
    #pragma unroll
    for (int t4 = t; t4 < 4096; t4 += 1024) {
        int col = t4 >> 6, k = t4 & 63;
        W2T[col * 64 + k] = f2bf(W2[k * 64 + col]);
    }
    uint32_t base = (uint32_t)t * 16u;
    const uint4* b4 = (const uint4*)(bsum + base);
    uint32_t sum = 0;
    #pragma unroll
    for (int k = 0; k < 4; ++k) { uint4 v = b4[k]; sum += v.x + v.y + v.z + v.w; }
    s[t] = sum;
    __syncthreads();
    for (int off = 1; off < 1024; off <<= 1) {
        uint32_t v = (t >= off) ? s[t - off] : 0u;
        __syncthreads();
        s[t] += v;
        __syncthreads();
    }
    uint32_t run = s[t] - sum;
    for (int k = 0; k < 16; ++k) { bscan[base + k] = run; run += bsum[base + k]; }
    if (t == 1023) bscan[16384] = run;
}

// Rank each point. ONE atomic (count) + plain 12B xyz store (exact for
// singletons). Second arrival of a voxel allocates a compact multi slot and
// lazily zeroes its msum/mfeat rows (so no big memset needed).
__global__ void k3a_rank(const float4* __restrict__ coords,
                         uint32_t* __restrict__ ranks,
                         const uint32_t* __restrict__ bitmap,
                         const uint16_t* __restrict__ scan4,
                         const uint32_t* __restrict__ bscan,
                         float* __restrict__ sums,      // [N][4] = {count, x, y, z}
                         uint32_t* __restrict__ inv,    // rank -> point
                         uint32_t* __restrict__ slotmap,
                         uint32_t* __restrict__ mctr,
                         float* __restrict__ msum,
                         float* __restrict__ mfeat,
                         float* __restrict__ out_sp, int N) {
    int i = blockIdx.x * blockDim.x + threadIdx.x;
    if (i >= N) return;
    float4 c = coords[i];
    uint32_t key = point_key(c);
    uint32_t w = key >> 5, bit = key & 31u;
    uint4 q = *(const uint4*)(bitmap + (w & ~3u));
    uint32_t wd[4] = {q.x, q.y, q.z, q.w};
    uint32_t idx = w & 3u;
    uint32_t r = bscan[w >> 10] + (uint32_t)scan4[w >> 2];
    uint32_t cur = 0;
    #pragma unroll
    for (uint32_t j = 0; j < 4; ++j) {
        r += (j < idx) ? __popc(wd[j]) : 0u;
        cur = (j == idx) ? wd[j] : cur;
    }
    r += __popc(cur & ((1u << bit) - 1u));
    ranks[i] = r;
    inv[r] = (uint32_t)i;
    out_sp[i] = (float)r;
    float* s4 = sums + 4u * (size_t)r;
    float old = atomicAdd(s4 + 0, 1.0f);
    s4[1] = c.y; s4[2] = c.z; s4[3] = c.w;
    if (old == 1.0f) {                       // exactly one allocator per multi voxel
        uint32_t slot = atomicAdd(mctr, 1u);
        if (slot < MCAP) {
            slotmap[r] = slot + 1u;
            float4 z = make_float4(0.f, 0.f, 0.f, 0.f);
            *(float4*)(msum + 4u * (size_t)slot) = z;
            float4* fz = (float4*)(mfeat + 64u * (size_t)slot);
            #pragma unroll
            for (int qq = 0; qq < 16; ++qq) fz[qq] = z;
        }
    }
}

// Fixup for multi voxels (~0.1% of points do work): accumulate xyz into msum
// and features/c into mfeat, in compact slot space. Runs AFTER k3a, BEFORE k5.
__global__ void k3fix(const float4* __restrict__ coords,
                      const float* __restrict__ features,
                      const uint32_t* __restrict__ ranks,
                      const uint32_t* __restrict__ slotmap,
                      const float4* __restrict__ sums,
                      float* __restrict__ msum,          // [MCAP][4]
                      float* __restrict__ mfeat, int N) { // [MCAP][64]
    int i = blockIdx.x * blockDim.x + threadIdx.x;
    if (i >= N) return;
    uint32_t r = ranks[i];
    uint32_t sl = slotmap[r];
    if (sl == 0) return;
    sl -= 1u;
    float cnt = sums[r].x;
    float4 c = coords[i];
    float* m = msum + 4u * (size_t)sl;
    atomicAdd(m + 0, c.y);
    atomicAdd(m + 1, c.z);
    atomicAdd(m + 2, c.w);
    float iv = 1.0f / cnt;
    const float* frow = features + (size_t)i * 64;
    float* orow = mfeat + (size_t)sl * 64;
    #pragma unroll 1
    for (int qq = 0; qq < 64; ++qq) atomicAdd(&orow[qq], frow[qq] * iv);
}

// Rank-centric fused epilogue — 32 ranks/wave (2 row-groups), 128 ranks/block.
// P^T via mfma(A=W2T-frag, B=h-frag): D[g][cg] rank-row = rows_base+16g+(lane&15),
// cols = 16cg+4*(lane>>4)+{0..3}. Feature gathers issued EARLY (clamped index,
// folded into acc init) so MFMA hides gather latency. Plain float4 stores.
// Halved per-wave state (acc 8 x f32x4) -> lower VGPR, more waves in flight.
// Fused k6: block 0 writes batch_offsets from bscan.
__global__ __launch_bounds__(256) void k5_fused(
        const f32x4* __restrict__ features4,
        const uint32_t* __restrict__ inv,
        const float4* __restrict__ sums,
        const uint32_t* __restrict__ slotmap,
        const float4* __restrict__ msum,
        const f32x4* __restrict__ mfeat4,
        const float* __restrict__ W1, const float* __restrict__ b1,
        const short* __restrict__ W2T, const float* __restrict__ b2,
        const uint32_t* __restrict__ bscan,
        f32x4* __restrict__ out_feat4, float* __restrict__ out_cent,
        float* __restrict__ out_off, int N) {
    int lane = threadIdx.x & 63;
    int rows_base = blockIdx.x * 128 + (threadIdx.x >> 6) * 32;

    // folded k6: batch_offsets (blocks-per-batch = 16384/4 = 1<<12)
    if (blockIdx.x == 0 && threadIdx.x < 5) {
        int t = threadIdx.x;
        uint32_t v = (t == 0) ? 0u : bscan[(uint32_t)t << 12];
        out_off[t] = (float)v;
    }

    // ---- sequential metadata loads, then EARLY random feature gathers ----
    float4 sg4[2]; float cntg[2]; uint32_t invg[2];
    #pragma unroll
    for (int g = 0; g < 2; ++g) {
        int rg = rows_base + (g << 4) + (lane & 15);
        int rgc = rg < N ? rg : N - 1;
        sg4[g] = sums[rgc];
        cntg[g] = sg4[g].x;
        invg[g] = inv[rgc];
    }
    f32x4 acc[2][4];
    #pragma unroll
    for (int g = 0; g < 2; ++g) {
        uint32_t sel = (cntg[g] > 0.f) ? invg[g] : 0u;   // cnt==0: harmless row 0
        size_t fb = (size_t)sel * 16 + (lane >> 4);
        #pragma unroll
        for (int cg = 0; cg < 4; ++cg) acc[g][cg] = features4[fb + (cg << 2)];
    }
    // acc = b2 + (cnt==1 ? feat : 0); non-singleton feat discarded here
    #pragma unroll
    for (int cg = 0; cg < 4; ++cg) {
        f32x4 bv = ((const f32x4*)b2)[(cg << 2) + (lane >> 4)];
        #pragma unroll
        for (int g = 0; g < 2; ++g)
            acc[g][cg] = (cntg[g] == 1.0f) ? (acc[g][cg] + bv) : bv;
    }

    // centers for the 2 row-groups (h B-fragments); multi rows from msum
    float scx[2], scy[2], scz[2];
    #pragma unroll
    for (int g = 0; g < 2; ++g) {
        int rg = rows_base + (g << 4) + (lane & 15);
        int rgc = rg < N ? rg : N - 1;
        float sx = sg4[g].y, sy = sg4[g].z, sz = sg4[g].w;
        if (cntg[g] > 1.5f) {
            float4 m = msum[slotmap[rgc] - 1u];
            sx = m.x; sy = m.y; sz = m.z;
        }
        float ic = cntg[g] > 0.f ? 1.f / cntg[g] : 0.f;
        scx[g] = sx * ic; scy[g] = sy * ic; scz[g] = sz * ic;
    }

    #pragma unroll
    for (int s = 0; s < 2; ++s) {
        int kb = s * 32 + ((lane >> 4) << 3);
        float4 tx0 = *(const float4*)(W1 + kb),       tx1 = *(const float4*)(W1 + kb + 4);
        float4 ty0 = *(const float4*)(W1 + 64 + kb),  ty1 = *(const float4*)(W1 + 64 + kb + 4);
        float4 tz0 = *(const float4*)(W1 + 128 + kb), tz1 = *(const float4*)(W1 + 128 + kb + 4);
        float4 tb0 = *(const float4*)(b1 + kb),       tb1 = *(const float4*)(b1 + kb + 4);
        float w1x[8] = {tx0.x, tx0.y, tx0.z, tx0.w, tx1.x, tx1.y, tx1.z, tx1.w};
        float w1y[8] = {ty0.x, ty0.y, ty0.z, ty0.w, ty1.x, ty1.y, ty1.z, ty1.w};
        float w1z[8] = {tz0.x, tz0.y, tz0.z, tz0.w, tz1.x, tz1.y, tz1.z, tz1.w};
        float b1v[8] = {tb0.x, tb0.y, tb0.z, tb0.w, tb1.x, tb1.y, tb1.z, tb1.w};

        short8 afrag[4];   // W2T A-fragments: A[col=lane&15 (+16cg)][k]
        #pragma unroll
        for (int cg = 0; cg < 4; ++cg) {
            int col = (cg << 4) | (lane & 15);
            afrag[cg] = *(const short8*)(W2T + col * 64 + kb);
        }

        #pragma unroll
        for (int g = 0; g < 2; ++g) {
            short8 hf;   // h B-fragment: B[k][row=lane&15 (+16g)]
            #pragma unroll
            for (int j = 0; j < 8; ++j) {
                float h = fmaf(scz[g], w1z[j], fmaf(scy[g], w1y[j], fmaf(scx[g], w1x[j], b1v[j])));
                hf[j] = f2bf(fmaxf(h, 0.0f));
            }
            #pragma unroll
            for (int cg = 0; cg < 4; ++cg)
                acc[g][cg] = __builtin_amdgcn_mfma_f32_16x16x32_bf16(afrag[cg], hf, acc[g][cg], 0, 0, 0);
        }
    }

    // own-rank centers output: lanes 0-31 cover the wave's 32 ranks (L1-hot)
    if (lane < 32) {
        int my = rows_base + lane;
        if (my < N) {
            float4 s4 = sums[my];
            float sx = s4.y, sy = s4.z, sz = s4.w;
            if (s4.x > 1.5f) {
                float4 m = msum[slotmap[my] - 1u];
                sx = m.x; sy = m.y; sz = m.z;
            }
            float ic = s4.x > 0.f ? 1.f / s4.x : 0.f;
            out_cent[3 * (size_t)my + 0] = sx * ic;
            out_cent[3 * (size_t)my + 1] = sy * ic;
            out_cent[3 * (size_t)my + 2] = sz * ic;
        }
    }

    // Epilogue: select + plain float4 stores (L2 merges the 4 cg-sectors).
    #pragma unroll
    for (int g = 0; g < 2; ++g) {
        int gr = rows_base + (g << 4) + (lane & 15);
        if (gr >= N) continue;
        float cnt = cntg[g];
        f32x4 v[4];
        #pragma unroll
        for (int cg = 0; cg < 4; ++cg) v[cg] = acc[g][cg];
        if (cnt == 0.0f) {
            #pragma unroll
            for (int cg = 0; cg < 4; ++cg) v[cg] = (f32x4){0.f, 0.f, 0.f, 0.f};
        } else if (cnt > 1.5f) {
            size_t mb = (size_t)(slotmap[gr] - 1u) * 16 + (lane >> 4);
            #pragma unroll
            for (int cg = 0; cg < 4; ++cg) v[cg] += mfeat4[mb + (cg << 2)];
        }
        size_t ob = (size_t)gr * 16 + (lane >> 4);
        #pragma unroll
        for (int cg = 0; cg < 4; ++cg)
            out_feat4[ob + (cg << 2)] = v[cg];
    }
}

extern "C" void kernel_launch(void* const* d_in, const int* in_sizes, int n_in,
                              void* d_out, int out_size, void* d_ws, size_t ws_size,
                              hipStream_t stream) {
    const float4* coords = (const float4*)d_in[0];
    const float*  feats  = (const float*)d_in[1];
    const float*  W1 = (const float*)d_in[2];
    const float*  b1 = (const float*)d_in[3];
    const float*  W2 = (const float*)d_in[4];
    const float*  b2 = (const float*)d_in[5];
    int N = in_sizes[0] / 4;

    char* ws = (char*)d_ws;
    size_t o = 0;
    uint32_t* bitmap = (uint32_t*)(ws + o); o += (size_t)NWORDS * 4;        // 64 MB
    uint16_t* scan4  = (uint16_t*)(ws + o); o += (size_t)(NWORDS / 4) * 2;  // 8 MB
    uint32_t* bsum   = (uint32_t*)(ws + o); o += (size_t)NBLK * 4;          // 64 KB
    uint32_t* bscan  = (uint32_t*)(ws + o); o += (size_t)(NBLK + 1) * 4;
    o = (o + 15) & ~(size_t)15;
    uint32_t* ranks  = (uint32_t*)(ws + o); o += (size_t)N * 4;
    o = (o + 15) & ~(size_t)15;
    float*    sums   = (float*)(ws + o);    o += (size_t)N * 16;            // {cnt,x,y,z}
    uint32_t* inv    = (uint32_t*)(ws + o); o += (size_t)N * 4;
    o = (o + 15) & ~(size_t)15;
    short*    W2T    = (short*)(ws + o);    o += 8192;
    // ---- multi region: only slotmap+mctr need memset (msum/mfeat lazy-zeroed) ----
    size_t multi_base = o;
    uint32_t* slotmap = (uint32_t*)(ws + o); o += (size_t)N * 4;
    uint32_t* mctr    = (uint32_t*)(ws + o); o += 16;
    size_t multi_size = o - multi_base;
    float*    msum    = (float*)(ws + o);    o += (size_t)MCAP * 16;
    float*    mfeat   = (float*)(ws + o);    o += (size_t)MCAP * 256;

    float* out_feat = (float*)d_out;
    float* out_cent = out_feat + (size_t)N * 64;
    float* out_sp   = out_cent + (size_t)N * 3;
    float* out_off  = out_sp + N;

    hipMemsetAsync(bitmap, 0, (size_t)NWORDS * 4, stream);
    hipMemsetAsync(sums, 0, (size_t)N * 16, stream);
    hipMemsetAsync(ws + multi_base, 0, multi_size, stream);

    int nb = (N + 255) / 256;
    int nb5 = (N + 127) / 128;
    k1_keys<<<nb, 256, 0, stream>>>(coords, bitmap, N);
    k2a_blockscan<<<NBLK, 256, 0, stream>>>((const uint4*)bitmap, scan4, bsum);
    k2b_topscan<<<1, 1024, 0, stream>>>(bsum, bscan, W2, W2T);
    k3a_rank<<<nb, 256, 0, stream>>>(coords, ranks, bitmap, scan4, bscan, sums, inv,
                                     slotmap, mctr, msum, mfeat, out_sp, N);
    k3fix<<<nb, 256, 0, stream>>>(coords, feats, ranks, slotmap, (const float4*)sums,
                                  msum, mfeat, N);
    k5_fused<<<nb5, 256, 0, stream>>>((const f32x4*)feats, inv, (const float4*)sums,
                                      slotmap, (const float4*)msum, (const f32x4*)mfeat,
                                      W1, b1, W2T, b2, bscan,
                                      (f32x4*)out_feat, out_cent, out_off, N);
}

// Round 15
// 321.516 us; speedup vs baseline: 1.0659x; 1.0659x over previous
//
#include <hip/hip_runtime.h>
#include <stdint.h>

// Superpoint pooling via 29-bit key bitmap + prefix-popcount ranking.
// key = batch(2b)|qx(9b)|qy(9b)|qz(9b); numeric order == lex order, so exclusive
// prefix popcount over the presence bitmap == jnp.unique sorted rank.
// R15: restore R13 exactly (measured best: 322 µs). R14's smaller tile
// regressed (occupancy is backpressure-pinned, not VGPR-limited; smaller
// tile just cut latency-hiding work per wave). k5 = 64 ranks/wave,
// early-gather, plain float4 stores; 1-atomic k3a; lazy-zero multi slots;
// k0 folded into k2b, k6 folded into k5.

static constexpr uint32_t NWORDS = 1u << 24;        // 2^29 bits / 32
static constexpr uint32_t NBLK   = NWORDS / 1024;   // 16384 scan blocks
static constexpr uint32_t MCAP   = 65536;           // multi-voxel slot capacity

typedef __attribute__((ext_vector_type(8))) short short8;
typedef __attribute__((ext_vector_type(4))) float f32x4;

__device__ __forceinline__ short f2bf(float x) {
    union { float f; uint32_t u; } v; v.f = x;
    uint32_t u = v.u;
    uint32_t r = (u + 0x7FFFu + ((u >> 16) & 1u)) >> 16;   // RNE
    return (short)r;
}

__device__ __forceinline__ uint32_t point_key(float4 c) {
    uint32_t b  = (uint32_t)(int)c.x;
    uint32_t qx = (uint32_t)(int)floorf(c.y / 0.1f);
    uint32_t qy = (uint32_t)(int)floorf(c.z / 0.1f);
    uint32_t qz = (uint32_t)(int)floorf(c.w / 0.1f);
    return (b << 27) | (qx << 18) | (qy << 9) | qz;
}

__global__ void k1_keys(const float4* __restrict__ coords, uint32_t* __restrict__ bitmap, int N) {
    int i = blockIdx.x * blockDim.x + threadIdx.x;
    if (i >= N) return;
    uint32_t key = point_key(coords[i]);
    atomicOr(&bitmap[key >> 5], 1u << (key & 31u));   // fire-and-forget: no read-back
}

// 1024 words/block, 256 threads, 4 words/thread via uint4, wave-shuffle scan.
// scan4[w>>2]: exclusive popcount prefix within block at 4-word granularity
// (max 255*128 = 32640, fits u16).
__global__ __launch_bounds__(256) void k2a_blockscan(
        const uint4* __restrict__ bm4, uint16_t* __restrict__ scan4,
        uint32_t* __restrict__ bsum) {
    int t = threadIdx.x;
    int lane = t & 63, wid = t >> 6;
    uint4 v = bm4[(size_t)blockIdx.x * 256 + t];
    uint32_t pc = __popc(v.x) + __popc(v.y) + __popc(v.z) + __popc(v.w);
    uint32_t sc = pc;
    #pragma unroll
    for (int off = 1; off < 64; off <<= 1) {
        uint32_t n = __shfl_up(sc, off);
        if (lane >= off) sc += n;
    }
    __shared__ uint32_t wt[4];
    if (lane == 63) wt[wid] = sc;
    __syncthreads();
    uint32_t wbase = 0;
    #pragma unroll
    for (int w = 0; w < 4; ++w) wbase += (w < wid) ? wt[w] : 0u;
    scan4[(size_t)blockIdx.x * 256 + t] = (uint16_t)(wbase + sc - pc);
    if (t == 255) bsum[blockIdx.x] = wbase + sc;
}

// Exclusive scan of 16384 block sums; bscan[16384] = total unique count U.
// Fused: W2 -> bf16 transposed (W2T[col*64+k] = bf16(W2[k*64+col])).
__global__ void k2b_topscan(const uint32_t* __restrict__ bsum, uint32_t* __restrict__ bscan,
                            const float* __restrict__ W2, short* __restrict__ W2T) {
    __shared__ uint32_t s[1024];
    int t = threadIdx.x;
    // folded k0: 4096 elements over 1024 threads
    #pragma unroll
    for (int t4 = t; t4 < 4096; t4 += 1024) {
        int col = t4 >> 6, k = t4 & 63;
        W2T[col * 64 + k] = f2bf(W2[k * 64 + col]);
    }
    uint32_t base = (uint32_t)t * 16u;
    const uint4* b4 = (const uint4*)(bsum + base);
    uint32_t sum = 0;
    #pragma unroll
    for (int k = 0; k < 4; ++k) { uint4 v = b4[k]; sum += v.x + v.y + v.z + v.w; }
    s[t] = sum;
    __syncthreads();
    for (int off = 1; off < 1024; off <<= 1) {
        uint32_t v = (t >= off) ? s[t - off] : 0u;
        __syncthreads();
        s[t] += v;
        __syncthreads();
    }
    uint32_t run = s[t] - sum;
    for (int k = 0; k < 16; ++k) { bscan[base + k] = run; run += bsum[base + k]; }
    if (t == 1023) bscan[16384] = run;
}

// Rank each point. ONE atomic (count) + plain 12B xyz store (exact for
// singletons). Second arrival of a voxel allocates a compact multi slot and
// lazily zeroes its msum/mfeat rows (so no big memset needed).
__global__ void k3a_rank(const float4* __restrict__ coords,
                         uint32_t* __restrict__ ranks,
                         const uint32_t* __restrict__ bitmap,
                         const uint16_t* __restrict__ scan4,
                         const uint32_t* __restrict__ bscan,
                         float* __restrict__ sums,      // [N][4] = {count, x, y, z}
                         uint32_t* __restrict__ inv,    // rank -> point
                         uint32_t* __restrict__ slotmap,
                         uint32_t* __restrict__ mctr,
                         float* __restrict__ msum,
                         float* __restrict__ mfeat,
                         float* __restrict__ out_sp, int N) {
    int i = blockIdx.x * blockDim.x + threadIdx.x;
    if (i >= N) return;
    float4 c = coords[i];
    uint32_t key = point_key(c);
    uint32_t w = key >> 5, bit = key & 31u;
    uint4 q = *(const uint4*)(bitmap + (w & ~3u));
    uint32_t wd[4] = {q.x, q.y, q.z, q.w};
    uint32_t idx = w & 3u;
    uint32_t r = bscan[w >> 10] + (uint32_t)scan4[w >> 2];
    uint32_t cur = 0;
    #pragma unroll
    for (uint32_t j = 0; j < 4; ++j) {
        r += (j < idx) ? __popc(wd[j]) : 0u;
        cur = (j == idx) ? wd[j] : cur;
    }
    r += __popc(cur & ((1u << bit) - 1u));
    ranks[i] = r;
    inv[r] = (uint32_t)i;
    out_sp[i] = (float)r;
    float* s4 = sums + 4u * (size_t)r;
    float old = atomicAdd(s4 + 0, 1.0f);
    s4[1] = c.y; s4[2] = c.z; s4[3] = c.w;
    if (old == 1.0f) {                       // exactly one allocator per multi voxel
        uint32_t slot = atomicAdd(mctr, 1u);
        if (slot < MCAP) {
            slotmap[r] = slot + 1u;
            float4 z = make_float4(0.f, 0.f, 0.f, 0.f);
            *(float4*)(msum + 4u * (size_t)slot) = z;
            float4* fz = (float4*)(mfeat + 64u * (size_t)slot);
            #pragma unroll
            for (int qq = 0; qq < 16; ++qq) fz[qq] = z;
        }
    }
}

// Fixup for multi voxels (~0.1% of points do work): accumulate xyz into msum
// and features/c into mfeat, in compact slot space. Runs AFTER k3a, BEFORE k5.
__global__ void k3fix(const float4* __restrict__ coords,
                      const float* __restrict__ features,
                      const uint32_t* __restrict__ ranks,
                      const uint32_t* __restrict__ slotmap,
                      const float4* __restrict__ sums,
                      float* __restrict__ msum,          // [MCAP][4]
                      float* __restrict__ mfeat, int N) { // [MCAP][64]
    int i = blockIdx.x * blockDim.x + threadIdx.x;
    if (i >= N) return;
    uint32_t r = ranks[i];
    uint32_t sl = slotmap[r];
    if (sl == 0) return;
    sl -= 1u;
    float cnt = sums[r].x;
    float4 c = coords[i];
    float* m = msum + 4u * (size_t)sl;
    atomicAdd(m + 0, c.y);
    atomicAdd(m + 1, c.z);
    atomicAdd(m + 2, c.w);
    float iv = 1.0f / cnt;
    const float* frow = features + (size_t)i * 64;
    float* orow = mfeat + (size_t)sl * 64;
    #pragma unroll 1
    for (int qq = 0; qq < 64; ++qq) atomicAdd(&orow[qq], frow[qq] * iv);
}

// Rank-centric fused epilogue, one wave = 64 consecutive ranks (R6/R13's k5).
// P^T via mfma(A=W2T-frag, B=h-frag): D[g][cg] rank-row = rows_base+16g+(lane&15),
// cols = 16cg+4*(lane>>4)+{0..3}. Feature gathers issued EARLY (clamped index,
// folded into acc init) so MFMA hides gather latency. Plain float4 stores.
// Fused k6: block 0 writes batch_offsets from bscan.
__global__ __launch_bounds__(256) void k5_fused(
        const f32x4* __restrict__ features4,
        const uint32_t* __restrict__ inv,
        const float4* __restrict__ sums,
        const uint32_t* __restrict__ slotmap,
        const float4* __restrict__ msum,
        const f32x4* __restrict__ mfeat4,
        const float* __restrict__ W1, const float* __restrict__ b1,
        const short* __restrict__ W2T, const float* __restrict__ b2,
        const uint32_t* __restrict__ bscan,
        f32x4* __restrict__ out_feat4, float* __restrict__ out_cent,
        float* __restrict__ out_off, int N) {
    int lane = threadIdx.x & 63;
    int rows_base = blockIdx.x * 256 + (threadIdx.x >> 6) * 64;

    // folded k6: batch_offsets (blocks-per-batch = 16384/4 = 1<<12)
    if (blockIdx.x == 0 && threadIdx.x < 5) {
        int t = threadIdx.x;
        uint32_t v = (t == 0) ? 0u : bscan[(uint32_t)t << 12];
        out_off[t] = (float)v;
    }

    // ---- sequential metadata loads, then EARLY random feature gathers ----
    float4 sg4[4]; float cntg[4]; uint32_t invg[4];
    #pragma unroll
    for (int g = 0; g < 4; ++g) {
        int rg = rows_base + (g << 4) + (lane & 15);
        int rgc = rg < N ? rg : N - 1;
        sg4[g] = sums[rgc];
        cntg[g] = sg4[g].x;
        invg[g] = inv[rgc];
    }
    f32x4 acc[4][4];
    #pragma unroll
    for (int g = 0; g < 4; ++g) {
        uint32_t sel = (cntg[g] > 0.f) ? invg[g] : 0u;   // cnt==0: harmless row 0
        size_t fb = (size_t)sel * 16 + (lane >> 4);
        #pragma unroll
        for (int cg = 0; cg < 4; ++cg) acc[g][cg] = features4[fb + (cg << 2)];
    }
    // acc = b2 + (cnt==1 ? feat : 0); non-singleton feat discarded here
    #pragma unroll
    for (int cg = 0; cg < 4; ++cg) {
        f32x4 bv = ((const f32x4*)b2)[(cg << 2) + (lane >> 4)];
        #pragma unroll
        for (int g = 0; g < 4; ++g)
            acc[g][cg] = (cntg[g] == 1.0f) ? (acc[g][cg] + bv) : bv;
    }

    // centers for the 16-row groups (h B-fragments); multi rows from msum
    float scx[4], scy[4], scz[4];
    #pragma unroll
    for (int g = 0; g < 4; ++g) {
        int rg = rows_base + (g << 4) + (lane & 15);
        int rgc = rg < N ? rg : N - 1;
        float sx = sg4[g].y, sy = sg4[g].z, sz = sg4[g].w;
        if (cntg[g] > 1.5f) {
            float4 m = msum[slotmap[rgc] - 1u];
            sx = m.x; sy = m.y; sz = m.z;
        }
        float ic = cntg[g] > 0.f ? 1.f / cntg[g] : 0.f;
        scx[g] = sx * ic; scy[g] = sy * ic; scz[g] = sz * ic;
    }

    #pragma unroll
    for (int s = 0; s < 2; ++s) {
        int kb = s * 32 + ((lane >> 4) << 3);
        float4 tx0 = *(const float4*)(W1 + kb),       tx1 = *(const float4*)(W1 + kb + 4);
        float4 ty0 = *(const float4*)(W1 + 64 + kb),  ty1 = *(const float4*)(W1 + 64 + kb + 4);
        float4 tz0 = *(const float4*)(W1 + 128 + kb), tz1 = *(const float4*)(W1 + 128 + kb + 4);
        float4 tb0 = *(const float4*)(b1 + kb),       tb1 = *(const float4*)(b1 + kb + 4);
        float w1x[8] = {tx0.x, tx0.y, tx0.z, tx0.w, tx1.x, tx1.y, tx1.z, tx1.w};
        float w1y[8] = {ty0.x, ty0.y, ty0.z, ty0.w, ty1.x, ty1.y, ty1.z, ty1.w};
        float w1z[8] = {tz0.x, tz0.y, tz0.z, tz0.w, tz1.x, tz1.y, tz1.z, tz1.w};
        float b1v[8] = {tb0.x, tb0.y, tb0.z, tb0.w, tb1.x, tb1.y, tb1.z, tb1.w};

        short8 afrag[4];   // W2T A-fragments: A[col=lane&15 (+16cg)][k]
        #pragma unroll
        for (int cg = 0; cg < 4; ++cg) {
            int col = (cg << 4) | (lane & 15);
            afrag[cg] = *(const short8*)(W2T + col * 64 + kb);
        }

        #pragma unroll
        for (int g = 0; g < 4; ++g) {
            short8 hf;   // h B-fragment: B[k][row=lane&15 (+16g)]
            #pragma unroll
            for (int j = 0; j < 8; ++j) {
                float h = fmaf(scz[g], w1z[j], fmaf(scy[g], w1y[j], fmaf(scx[g], w1x[j], b1v[j])));
                hf[j] = f2bf(fmaxf(h, 0.0f));
            }
            #pragma unroll
            for (int cg = 0; cg < 4; ++cg)
                acc[g][cg] = __builtin_amdgcn_mfma_f32_16x16x32_bf16(afrag[cg], hf, acc[g][cg], 0, 0, 0);
        }
    }

    // own-rank centers output (independent of MFMA; multi rows from msum)
    int my = rows_base + lane;
    if (my < N) {
        float4 s4 = sums[my];          // L1-hot (same 1KB as sg4)
        float sx = s4.y, sy = s4.z, sz = s4.w;
        if (s4.x > 1.5f) {
            float4 m = msum[slotmap[my] - 1u];
            sx = m.x; sy = m.y; sz = m.z;
        }
        float ic = s4.x > 0.f ? 1.f / s4.x : 0.f;
        out_cent[3 * (size_t)my + 0] = sx * ic;
        out_cent[3 * (size_t)my + 1] = sy * ic;
        out_cent[3 * (size_t)my + 2] = sz * ic;
    }

    // Epilogue: select + plain float4 stores (L2 merges the 4 cg-sectors).
    #pragma unroll
    for (int g = 0; g < 4; ++g) {
        int gr = rows_base + (g << 4) + (lane & 15);
        if (gr >= N) continue;
        float cnt = cntg[g];
        f32x4 v[4];
        #pragma unroll
        for (int cg = 0; cg < 4; ++cg) v[cg] = acc[g][cg];
        if (cnt == 0.0f) {
            #pragma unroll
            for (int cg = 0; cg < 4; ++cg) v[cg] = (f32x4){0.f, 0.f, 0.f, 0.f};
        } else if (cnt > 1.5f) {
            size_t mb = (size_t)(slotmap[gr] - 1u) * 16 + (lane >> 4);
            #pragma unroll
            for (int cg = 0; cg < 4; ++cg) v[cg] += mfeat4[mb + (cg << 2)];
        }
        size_t ob = (size_t)gr * 16 + (lane >> 4);
        #pragma unroll
        for (int cg = 0; cg < 4; ++cg)
            out_feat4[ob + (cg << 2)] = v[cg];
    }
}

extern "C" void kernel_launch(void* const* d_in, const int* in_sizes, int n_in,
                              void* d_out, int out_size, void* d_ws, size_t ws_size,
                              hipStream_t stream) {
    const float4* coords = (const float4*)d_in[0];
    const float*  feats  = (const float*)d_in[1];
    const float*  W1 = (const float*)d_in[2];
    const float*  b1 = (const float*)d_in[3];
    const float*  W2 = (const float*)d_in[4];
    const float*  b2 = (const float*)d_in[5];
    int N = in_sizes[0] / 4;

    char* ws = (char*)d_ws;
    size_t o = 0;
    uint32_t* bitmap = (uint32_t*)(ws + o); o += (size_t)NWORDS * 4;        // 64 MB
    uint16_t* scan4  = (uint16_t*)(ws + o); o += (size_t)(NWORDS / 4) * 2;  // 8 MB
    uint32_t* bsum   = (uint32_t*)(ws + o); o += (size_t)NBLK * 4;          // 64 KB
    uint32_t* bscan  = (uint32_t*)(ws + o); o += (size_t)(NBLK + 1) * 4;
    o = (o + 15) & ~(size_t)15;
    uint32_t* ranks  = (uint32_t*)(ws + o); o += (size_t)N * 4;
    o = (o + 15) & ~(size_t)15;
    float*    sums   = (float*)(ws + o);    o += (size_t)N * 16;            // {cnt,x,y,z}
    uint32_t* inv    = (uint32_t*)(ws + o); o += (size_t)N * 4;
    o = (o + 15) & ~(size_t)15;
    short*    W2T    = (short*)(ws + o);    o += 8192;
    // ---- multi region: only slotmap+mctr need memset (msum/mfeat lazy-zeroed) ----
    size_t multi_base = o;
    uint32_t* slotmap = (uint32_t*)(ws + o); o += (size_t)N * 4;
    uint32_t* mctr    = (uint32_t*)(ws + o); o += 16;
    size_t multi_size = o - multi_base;
    float*    msum    = (float*)(ws + o);    o += (size_t)MCAP * 16;
    float*    mfeat   = (float*)(ws + o);    o += (size_t)MCAP * 256;

    float* out_feat = (float*)d_out;
    float* out_cent = out_feat + (size_t)N * 64;
    float* out_sp   = out_cent + (size_t)N * 3;
    float* out_off  = out_sp + N;

    hipMemsetAsync(bitmap, 0, (size_t)NWORDS * 4, stream);
    hipMemsetAsync(sums, 0, (size_t)N * 16, stream);
    hipMemsetAsync(ws + multi_base, 0, multi_size, stream);

    int nb = (N + 255) / 256;
    k1_keys<<<nb, 256, 0, stream>>>(coords, bitmap, N);
    k2a_blockscan<<<NBLK, 256, 0, stream>>>((const uint4*)bitmap, scan4, bsum);
    k2b_topscan<<<1, 1024, 0, stream>>>(bsum, bscan, W2, W2T);
    k3a_rank<<<nb, 256, 0, stream>>>(coords, ranks, bitmap, scan4, bscan, sums, inv,
                                     slotmap, mctr, msum, mfeat, out_sp, N);
    k3fix<<<nb, 256, 0, stream>>>(coords, feats, ranks, slotmap, (const float4*)sums,
                                  msum, mfeat, N);
    k5_fused<<<nb, 256, 0, stream>>>((const f32x4*)feats, inv, (const float4*)sums,
                                     slotmap, (const float4*)msum, (const f32x4*)mfeat,
                                     W1, b1, W2T, b2, bscan,
                                     (f32x4*)out_feat, out_cent, out_off, N);
}